// Round 2
// baseline (263.753 us; speedup 1.0000x reference)
//
#include <hip/hip_runtime.h>
#include <hip/hip_bf16.h>

// MHA: B=2 S=2048 D=768 H=12 DK=64. fp32 in/out; bf16 MFMA internally.
#define B_  2
#define S_  2048
#define D_  768
#define H_  12
#define DK_ 64
#define NX_ (B_*S_*D_)      // 3145728 activation elements
#define NW_ (D_*D_)         // 589824 weight elements
#define CSC 0.18033688011112042f   // 0.125 * log2(e), baked into wq/bq

typedef __attribute__((ext_vector_type(8))) short  bf16x8;
typedef __attribute__((ext_vector_type(4))) float  f32x4;
typedef __attribute__((ext_vector_type(16))) float f32x16;

__device__ __forceinline__ unsigned short f2bf(float f) {
    unsigned int u = __float_as_uint(f);
    u += 0x7fffu + ((u >> 16) & 1u);   // RNE
    return (unsigned short)(u >> 16);
}

// pack two fp32 -> {lo: bf16(a), hi: bf16(b)} in ONE VALU op (no builtin; asm)
__device__ __forceinline__ unsigned cvtpk(float a, float b) {
    unsigned r;
    asm("v_cvt_pk_bf16_f32 %0, %1, %2" : "=v"(r) : "v"(a), "v"(b));
    return r;
}

// v_permlane32_swap: dst.hi(lanes32-63) <-> src.lo(lanes0-31)
// new_a = {a.lo, b.lo}, new_b = {a.hi, b.hi}
__device__ __forceinline__ void plswap(unsigned &a, unsigned &b) {
    asm("v_permlane32_swap_b32 %0, %1" : "+v"(a), "+v"(b));
}

__device__ __forceinline__ void async_cp16(const unsigned short* g,
                                           const unsigned short* lds_uniform_base) {
    __builtin_amdgcn_global_load_lds(
        (const __attribute__((address_space(1))) unsigned int*)(uintptr_t)g,
        (__attribute__((address_space(3))) unsigned int*)(unsigned int)(uintptr_t)lds_uniform_base,
        16, 0, 0);
}

// ---------------------------------------------------------------------------
// Fused fp32->bf16 cvt, xor-swizzled per 64-el k-block (group g8 -> g8^(n&7)).
// 16 elements/thread. 1D grid: 3*768 activation blocks + 4*144 weight blocks.
// ---------------------------------------------------------------------------
struct CvtArgs { const float* s[7]; };

__global__ __launch_bounds__(256) void cvt_all(CvtArgs a,
                                               unsigned short* __restrict__ Xsw,
                                               unsigned short* __restrict__ Wsw) {
    const int bx = blockIdx.x;
    int y, inner;
    if (bx < 2304) { y = bx / 768;             inner = bx % 768; }
    else           { y = 3 + (bx - 2304) / 144; inner = (bx - 2304) % 144; }
    const int idx = inner * 256 + threadIdx.x;
    const int n  = idx / 48;
    const int g2 = idx % 48;                  // 16-el group in row
    const float* src = a.s[y] + (long)n * D_ + g2 * 16;
    const float zs = (y == 3) ? CSC : 1.0f;
    unsigned short o[16];
#pragma unroll
    for (int i = 0; i < 4; i++) {
        const float4 f = *(const float4*)(src + i * 4);
        o[i*4+0] = f2bf(f.x*zs); o[i*4+1] = f2bf(f.y*zs);
        o[i*4+2] = f2bf(f.z*zs); o[i*4+3] = f2bf(f.w*zs);
    }
    unsigned short* dst = (y >= 3) ? (Wsw + (long)(y - 3) * NW_ + (long)n * D_)
                                   : (Xsw + (long)y * NX_ + (long)n * D_);
    const int key = n & 7;
#pragma unroll
    for (int h = 0; h < 2; h++) {
        const int g8 = g2 * 2 + h;
        const int kdst = (g8 >> 3) * 64 + (((g8 & 7) ^ key) * 8);
        *(uint4*)(dst + kdst) = *(const uint4*)&o[h * 8];
    }
}

// ---------------------------------------------------------------------------
// Fused QKV projection. grid(32, 18): y -> zz = y/6, nb = y%6. Tile 128x128,
// BK=64, 4 waves 2x2. Both operands async-staged from swizzled bf16 global.
// Outputs: Q/K [bh][s][dk]; V transposed [bh][dk][s] (TRUE seq order now —
// attention keeps P in registers with true key order, pi-permute dropped).
// ---------------------------------------------------------------------------
struct QkvArgs { const float* bias[3]; unsigned short* out[3]; };

__global__ __launch_bounds__(256, 3) void gemm_qkv(QkvArgs args,
                                                   const unsigned short* __restrict__ Xsw,
                                                   const unsigned short* __restrict__ Wsw) {
    __shared__ __align__(16) unsigned short smem[17408];
    unsigned short* As = smem;           // [128][64] swizzled
    unsigned short* Bs = smem + 8192;    // [128][64] swizzled

    const int t    = threadIdx.x;
    const int wave = t >> 6;
    const int lane = t & 63;
    const int l16  = lane & 15;
    const int quad = lane >> 4;
    const int wm   = wave >> 1, wn = wave & 1;
    const int m0   = blockIdx.x * 128;
    const int zz   = blockIdx.y / 6;
    const int nb   = blockIdx.y % 6;
    const int n0   = nb * 128;

    const unsigned short* Ap = Xsw + (long)zz * NX_;
    const unsigned short* Wp = Wsw + (long)zz * NW_;

    f32x4 acc[4][4];
#pragma unroll
    for (int s = 0; s < 4; s++)
#pragma unroll
        for (int j = 0; j < 4; j++) acc[s][j] = (f32x4){0.f, 0.f, 0.f, 0.f};

    const int lrow = lane >> 3;
    const int lcg  = lane & 7;

    for (int k0 = 0; k0 < D_; k0 += 64) {
        __syncthreads();
#pragma unroll
        for (int i = 0; i < 4; i++) {
            const int chunk = wave * 4 + i;
            async_cp16(Ap + (long)(m0 + chunk * 8 + lrow) * D_ + k0 + lcg * 8,
                       As + chunk * 512);
        }
#pragma unroll
        for (int i = 0; i < 4; i++) {
            const int chunk = wave * 4 + i;
            async_cp16(Wp + (long)(n0 + chunk * 8 + lrow) * D_ + k0 + lcg * 8,
                       Bs + chunk * 512);
        }
        __syncthreads();
#pragma unroll
        for (int ks = 0; ks < 2; ks++) {
            const int cg = ks * 4 + quad;
            bf16x8 af[4], bf[4];
#pragma unroll
            for (int s = 0; s < 4; s++) {
                const int r = wm * 64 + s * 16 + l16;
                af[s] = *(const bf16x8*)&As[r * 64 + ((cg ^ (r & 7)) * 8)];
            }
#pragma unroll
            for (int j = 0; j < 4; j++) {
                const int r = wn * 64 + j * 16 + l16;
                bf[j] = *(const bf16x8*)&Bs[r * 64 + ((cg ^ (r & 7)) * 8)];
            }
#pragma unroll
            for (int s = 0; s < 4; s++)
#pragma unroll
                for (int j = 0; j < 4; j++)
                    acc[s][j] = __builtin_amdgcn_mfma_f32_16x16x32_bf16(af[s], bf[j], acc[s][j], 0, 0, 0);
        }
    }
    __syncthreads();

    const int b     = m0 >> 11;
    const int sbase = m0 & (S_ - 1);
    const float zs  = (zz == 0) ? CSC : 1.0f;
    float bv[4];
#pragma unroll
    for (int j = 0; j < 4; j++) bv[j] = args.bias[zz][n0 + wn * 64 + j * 16 + l16] * zs;

    if (zz < 2) {
        unsigned short* Ls = smem;       // [128][136]
#pragma unroll
        for (int s = 0; s < 4; s++)
#pragma unroll
            for (int j = 0; j < 4; j++)
#pragma unroll
                for (int r = 0; r < 4; r++)
                    Ls[(wm * 64 + s * 16 + quad * 4 + r) * 136 + wn * 64 + j * 16 + l16] =
                        f2bf(acc[s][j][r] + bv[j]);
        __syncthreads();
        const int row  = t >> 1;
        const int half = t & 1;
        unsigned short* Op = args.out[zz];
#pragma unroll
        for (int i = 0; i < 8; i++) {
            const int col  = half * 64 + i * 8;
            const int head = nb * 2 + half;
            const uint4 v = *(const uint4*)&Ls[row * 136 + col];
            *(uint4*)(Op + ((long)(b * H_ + head) * S_ + sbase + row) * DK_ + (col & 63)) = v;
        }
    } else {
        unsigned short* Ls = smem;       // [2][64][136]
#pragma unroll
        for (int s = 0; s < 4; s++)
#pragma unroll
            for (int j = 0; j < 4; j++)
#pragma unroll
                for (int r = 0; r < 4; r++) {
                    const int dk  = j * 16 + l16;
                    const int pos = wm * 64 + s * 16 + quad * 4 + r;   // TRUE seq order
                    Ls[wn * 8704 + dk * 136 + pos] = f2bf(acc[s][j][r] + bv[j]);
                }
        __syncthreads();
        const int rowIdx = t >> 1;
        const int hh = rowIdx >> 6, dk = rowIdx & 63;
        const int half = t & 1;
        unsigned short* Op = args.out[2];
#pragma unroll
        for (int i = 0; i < 8; i++) {
            const int col = half * 64 + i * 8;
            const uint4 v = *(const uint4*)&Ls[hh * 8704 + dk * 136 + col];
            const int head = nb * 2 + hh;
            *(uint4*)(Op + ((long)(b * H_ + head) * DK_ + dk) * S_ + sbase + col) = v;
        }
    }
}

// ---------------------------------------------------------------------------
// Flash attention v2: 32x32x16 MFMA, swapped QK^T (S^T = K Q^T) so each lane
// owns one query column; P stays IN REGISTERS via cvt_pk_bf16 + permlane32_swap
// (T12). 4 waves = 2 q-blocks x 2 key-halves of a 64-key tile; grid (32,24)
// = 768 = 3/CU, 12 waves/CU. Padded [64][68] K/V LDS tiles (conflict-free),
// rolling-pointer register prefetch, 1 barrier/tile. LDS traffic: 12 B/qk
// vs 23.4 B/qk before, P round-trip eliminated.
// ---------------------------------------------------------------------------
__global__ __launch_bounds__(256, 3) void attn_kernel(
    const unsigned short* __restrict__ Q, const unsigned short* __restrict__ K,
    const unsigned short* __restrict__ Vt, unsigned short* __restrict__ Ao)
{
    const int t    = threadIdx.x;
    const int wave = t >> 6;
    const int lane = t & 63;
    const int l31  = lane & 31;
    const int hi   = lane >> 5;
    const int wq   = wave & 1;          // q-block within 64-row tile
    const int wk   = wave >> 1;         // key-half within 64-key tile
    const int qtile = blockIdx.x;       // 32 tiles of 64 rows
    const int bh    = blockIdx.y;       // 24

    const unsigned short* Qp = Q  + (long)bh * S_ * DK_;
    const unsigned short* Kp = K  + (long)bh * S_ * DK_;
    const unsigned short* Vp = Vt + (long)bh * DK_ * S_;

    // K dbuf [2][64][68] @ 0, V dbuf [2][64][68] @ 8704 (short offsets)
    __shared__ __align__(16) unsigned short smem[17408];   // 34816 B

    // Q fragments (B-operand): B[n=query=l31][k=hi*8+j], k-slice ks*16
    bf16x8 qf[4];
    {
        const long qbase = (long)(qtile * 64 + wq * 32 + l31) * DK_ + hi * 8;
#pragma unroll
        for (int ks = 0; ks < 4; ks++)
            qf[ks] = *(const bf16x8*)(Qp + qbase + ks * 16);
    }

    // staging: thread -> row t>>2 (0..63), col (t&3)*16; 32 B each of K and V
    const int so = (t >> 2) * 68 + (t & 3) * 16;
    const unsigned short* gk = Kp + (t >> 2) * DK_ + (t & 3) * 16;
    const unsigned short* gv = Vp + (long)(t >> 2) * S_ + (t & 3) * 16;
    uint4 kreg[2], vreg[2];
    kreg[0] = *(const uint4*)gk;  kreg[1] = *(const uint4*)(gk + 8);
    vreg[0] = *(const uint4*)gv;  vreg[1] = *(const uint4*)(gv + 8);
    gk += 64 * DK_;  gv += 64;
    *(uint4*)&smem[so]            = kreg[0];
    *(uint4*)&smem[so + 8]        = kreg[1];
    *(uint4*)&smem[8704 + so]     = vreg[0];
    *(uint4*)&smem[8704 + so + 8] = vreg[1];

    f32x16 oacc[2];
#pragma unroll
    for (int jb = 0; jb < 2; jb++)
#pragma unroll
        for (int i = 0; i < 16; i++) oacc[jb][i] = 0.f;
    float lsum = 0.f;

    for (int it = 0; it < 32; ++it) {
        const int co = (it & 1) * 4352;          // current buffer (shorts)
        const int no = 4352 - co;                // next buffer
        __syncthreads();
        const unsigned short* Ks = smem + co;
        const unsigned short* Vs = smem + 8704 + co;

        if (it < 31) {                   // prefetch next tile into registers
            kreg[0] = *(const uint4*)gk;  kreg[1] = *(const uint4*)(gk + 8);
            vreg[0] = *(const uint4*)gv;  vreg[1] = *(const uint4*)(gv + 8);
            gk += 64 * DK_;  gv += 64;
        }

        // S^T = K Q^T : A[m=key(local32)=l31][k], B[n=query=l31][k]
        f32x16 sacc;
#pragma unroll
        for (int i = 0; i < 16; i++) sacc[i] = 0.f;
#pragma unroll
        for (int ks = 0; ks < 4; ks++) {
            const bf16x8 kf = *(const bf16x8*)&Ks[(wk * 32 + l31) * 68 + ks * 16 + hi * 8];
            sacc = __builtin_amdgcn_mfma_f32_32x32x16_bf16(kf, qf[ks], sacc, 0, 0, 0);
        }

        // p = exp2(s); lane holds P[query=l31][key = (r&3)+8*(r>>2)+4*hi (+16/24)]
        float p[16];
#pragma unroll
        for (int r = 0; r < 16; r++) p[r] = exp2f(sacc[r]);
        {
            const float s0 = (p[0] + p[1]) + (p[2] + p[3]);
            const float s1 = (p[4] + p[5]) + (p[6] + p[7]);
            const float s2 = (p[8] + p[9]) + (p[10] + p[11]);
            const float s3 = (p[12] + p[13]) + (p[14] + p[15]);
            lsum += (s0 + s1) + (s2 + s3);
        }

        // In-register PV A-fragments: frag[ks2] = P[q=l31][key = ks2*16+hi*8+j]
        unsigned a0 = cvtpk(p[0],  p[1]),  a1 = cvtpk(p[2],  p[3]);
        unsigned b0 = cvtpk(p[4],  p[5]),  b1 = cvtpk(p[6],  p[7]);
        unsigned c0 = cvtpk(p[8],  p[9]),  c1 = cvtpk(p[10], p[11]);
        unsigned d0 = cvtpk(p[12], p[13]), d1 = cvtpk(p[14], p[15]);
        plswap(a0, b0);  plswap(a1, b1);   // -> words (0,2) and (1,3) of frag0
        plswap(c0, d0);  plswap(c1, d1);   // -> words (0,2) and (1,3) of frag1
        uint4 pq0 = {a0, a1, b0, b1};
        uint4 pq1 = {c0, c1, d0, d1};
        const bf16x8 pa0 = *(const bf16x8*)&pq0;
        const bf16x8 pa1 = *(const bf16x8*)&pq1;

        // O += P V : B[k=key][n=dk] from V^T tile
#pragma unroll
        for (int ks2 = 0; ks2 < 2; ks2++) {
            const bf16x8 pf = ks2 ? pa1 : pa0;
#pragma unroll
            for (int jb = 0; jb < 2; jb++) {
                const bf16x8 vf = *(const bf16x8*)&Vs[(jb * 32 + l31) * 68 + wk * 32 + ks2 * 16 + hi * 8];
                oacc[jb] = __builtin_amdgcn_mfma_f32_32x32x16_bf16(pf, vf, oacc[jb], 0, 0, 0);
            }
        }

        if (it < 31) {                   // commit prefetch to other buffer
            *(uint4*)&smem[no + so]            = kreg[0];
            *(uint4*)&smem[no + so + 8]        = kreg[1];
            *(uint4*)&smem[8704 + no + so]     = vreg[0];
            *(uint4*)&smem[8704 + no + so + 8] = vreg[1];
        }
    }

    // combine key-halves: wk=1 dumps partials, wk=0 reduces + writes out
    lsum += __shfl_xor(lsum, 32, 64);                 // cross-hi: full half-sum per query
    __syncthreads();                                   // all K/V reads done; reuse LDS
    float* LoF = (float*)smem;                         // [2][32][64] f32 partial O (16 KB)
    float* Ll  = (float*)(smem + 8192);                // [2][32] f32 partial lsum

    if (wk == 1) {
#pragma unroll
        for (int jb = 0; jb < 2; jb++)
#pragma unroll
            for (int r = 0; r < 16; r++) {
                const int qloc = (r & 3) + 8 * (r >> 2) + 4 * hi;
                LoF[(wq * 32 + qloc) * 64 + jb * 32 + l31] = oacc[jb][r];
            }
        Ll[wq * 32 + l31] = lsum;
    }
    __syncthreads();
    if (wk == 0) {
#pragma unroll
        for (int jb = 0; jb < 2; jb++)
#pragma unroll
            for (int r = 0; r < 16; r++) {
                const int qloc = (r & 3) + 8 * (r >> 2) + 4 * hi;
                oacc[jb][r] += LoF[(wq * 32 + qloc) * 64 + jb * 32 + l31];
            }
        const float inv = 1.f / (lsum + Ll[wq * 32 + l31]);
        float scl[16];
#pragma unroll
        for (int r = 0; r < 16; r++)
            scl[r] = __shfl(inv, (r & 3) + 8 * (r >> 2) + 4 * hi, 64);

        // bf16 via wave-local LDS scratch [32][72] (in V region), swizzled out
        unsigned short* scr = smem + 8704 + wq * 2304;
#pragma unroll
        for (int jb = 0; jb < 2; jb++)
#pragma unroll
            for (int r = 0; r < 16; r++) {
                const int qloc = (r & 3) + 8 * (r >> 2) + 4 * hi;
                scr[qloc * 72 + jb * 32 + l31] = f2bf(oacc[jb][r] * scl[r]);
            }
        const int row  = lane >> 1;                    // 0..31
        const int half = lane & 1;
        const int qrow = qtile * 64 + wq * 32 + row;
        const int key  = qrow & 7;
        const int b = bh / H_, h = bh % H_;
        unsigned short* dst = Ao + (long)(b * S_ + qrow) * D_ + h * DK_;
#pragma unroll
        for (int i = 0; i < 4; i++) {
            const int g8 = half * 4 + i;
            const uint4 v = *(const uint4*)&scr[row * 72 + half * 32 + i * 8];
            *(uint4*)(dst + ((g8 ^ key) * 8)) = v;
        }
    }
}

// ---------------------------------------------------------------------------
// Output projection: Ao_sw bf16 @ Wo_sw -> fp32 d_out + bias. Tile 64x64,
// grid (64,12)=768 = 3/CU; launch_bounds(256,4) so all blocks resident.
// 4 waves 2x2 (wave 32x32), both operands async. Single-pass LDS epilogue.
// ---------------------------------------------------------------------------
__global__ __launch_bounds__(256, 4) void gemm_out(
    const unsigned short* __restrict__ A, const unsigned short* __restrict__ Wsw,
    const float* __restrict__ bias, float* __restrict__ Out)
{
    __shared__ __align__(16) unsigned short smem[8704];
    unsigned short* As = smem;           // [64][64] swizzled
    unsigned short* Bs = smem + 4096;    // [64][64] swizzled

    const int t    = threadIdx.x;
    const int wave = t >> 6;
    const int lane = t & 63;
    const int l16  = lane & 15;
    const int quad = lane >> 4;
    const int wm   = wave >> 1, wn = wave & 1;
    const int m0   = blockIdx.x * 64;
    const int n0   = blockIdx.y * 64;

    f32x4 acc[2][2];
#pragma unroll
    for (int s = 0; s < 2; s++)
#pragma unroll
        for (int j = 0; j < 2; j++) acc[s][j] = (f32x4){0.f, 0.f, 0.f, 0.f};

    const int lrow = lane >> 3;
    const int lcg  = lane & 7;

    for (int k0 = 0; k0 < D_; k0 += 64) {
        __syncthreads();
#pragma unroll
        for (int i = 0; i < 2; i++) {
            const int chunk = wave * 2 + i;
            async_cp16(A + (long)(m0 + chunk * 8 + lrow) * D_ + k0 + lcg * 8,
                       As + chunk * 512);
        }
#pragma unroll
        for (int i = 0; i < 2; i++) {
            const int chunk = wave * 2 + i;
            async_cp16(Wsw + (long)(n0 + chunk * 8 + lrow) * D_ + k0 + lcg * 8,
                       Bs + chunk * 512);
        }
        __syncthreads();
#pragma unroll
        for (int ks = 0; ks < 2; ks++) {
            const int cg = ks * 4 + quad;
            bf16x8 af[2], bf[2];
#pragma unroll
            for (int s = 0; s < 2; s++) {
                const int r = wm * 32 + s * 16 + l16;
                af[s] = *(const bf16x8*)&As[r * 64 + ((cg ^ (r & 7)) * 8)];
            }
#pragma unroll
            for (int j = 0; j < 2; j++) {
                const int r = wn * 32 + j * 16 + l16;
                bf[j] = *(const bf16x8*)&Bs[r * 64 + ((cg ^ (r & 7)) * 8)];
            }
#pragma unroll
            for (int s = 0; s < 2; s++)
#pragma unroll
                for (int j = 0; j < 2; j++)
                    acc[s][j] = __builtin_amdgcn_mfma_f32_16x16x32_bf16(af[s], bf[j], acc[s][j], 0, 0, 0);
        }
    }

    float bv[2];
#pragma unroll
    for (int j = 0; j < 2; j++) bv[j] = bias[n0 + wn * 32 + j * 16 + l16];

    __syncthreads();                     // done with As/Bs before reuse
    float* fl = (float*)smem;            // [64][67]
#pragma unroll
    for (int s = 0; s < 2; s++)
#pragma unroll
        for (int j = 0; j < 2; j++)
#pragma unroll
            for (int r = 0; r < 4; r++)
                fl[(wm * 32 + s * 16 + quad * 4 + r) * 67 + wn * 32 + j * 16 + l16] =
                    acc[s][j][r] + bv[j];
    __syncthreads();
    const int row = t >> 2, c0 = (t & 3) * 16;
#pragma unroll
    for (int i = 0; i < 4; i++) {
        const float4 v = *(const float4*)&fl[row * 67 + c0 + i * 4];
        *(float4*)(Out + (long)(m0 + row) * D_ + n0 + c0 + i * 4) = v;
    }
}

extern "C" void kernel_launch(void* const* d_in, const int* in_sizes, int n_in,
                              void* d_out, int out_size, void* d_ws, size_t ws_size,
                              hipStream_t stream) {
    const float* k_in = (const float*)d_in[0];
    const float* q_in = (const float*)d_in[1];
    const float* v_in = (const float*)d_in[2];
    // d_in[3] = mask: no-op per reference
    const float* wq = (const float*)d_in[4];
    const float* bq = (const float*)d_in[5];
    const float* wk = (const float*)d_in[6];
    const float* bk = (const float*)d_in[7];
    const float* wv = (const float*)d_in[8];
    const float* bv = (const float*)d_in[9];
    const float* wo = (const float*)d_in[10];
    const float* bo = (const float*)d_in[11];

    unsigned short* ws = (unsigned short*)d_ws;
    unsigned short* Wsw = ws;                          // 4*NW bf16 swizzled
    unsigned short* Qb  = Wsw + 4ll * NW_;             // NX bf16
    unsigned short* Kb  = Qb + (long)NX_;
    unsigned short* Vt  = Kb + (long)NX_;
    unsigned short* Xsw = Vt + (long)NX_;              // 3*NX (dead after qkv)
    unsigned short* Ao  = Xsw;                         // aliases Xsw

    CvtArgs ca;
    ca.s[0] = q_in; ca.s[1] = k_in; ca.s[2] = v_in;
    ca.s[3] = wq;   ca.s[4] = wk;   ca.s[5] = wv;  ca.s[6] = wo;
    cvt_all<<<dim3(2880), 256, 0, stream>>>(ca, Xsw, Wsw);

    QkvArgs qa;
    qa.bias[0] = bq; qa.bias[1] = bk; qa.bias[2] = bv;
    qa.out[0] = Qb;  qa.out[1] = Kb;  qa.out[2] = Vt;
    gemm_qkv<<<dim3(32, 18), 256, 0, stream>>>(qa, Xsw, Wsw);

    attn_kernel<<<dim3(S_ / 64, B_ * H_), 256, 0, stream>>>(Qb, Kb, Vt, Ao);

    gemm_out<<<dim3(64, 12), 256, 0, stream>>>(Ao, Wsw + 3ll * NW_, bo, (float*)d_out);
}

// Round 3
// 215.359 us; speedup vs baseline: 1.2247x; 1.2247x over previous
//
#include <hip/hip_runtime.h>
#include <hip/hip_bf16.h>

// MHA: B=2 S=2048 D=768 H=12 DK=64. fp32 in/out; bf16 MFMA internally.
#define B_  2
#define S_  2048
#define D_  768
#define H_  12
#define DK_ 64
#define NX_ (B_*S_*D_)      // 3145728 activation elements
#define NW_ (D_*D_)         // 589824 weight elements
#define CSC 0.18033688011112042f   // 0.125 * log2(e), baked into wq/bq

typedef __attribute__((ext_vector_type(8))) short  bf16x8;
typedef __attribute__((ext_vector_type(4))) float  f32x4;

__device__ __forceinline__ unsigned short f2bf(float f) {
    unsigned int u = __float_as_uint(f);
    u += 0x7fffu + ((u >> 16) & 1u);   // RNE
    return (unsigned short)(u >> 16);
}

// pack two fp32 -> two bf16 (+0x8000 then hi16) in 3 VALU ops
__device__ __forceinline__ unsigned pack_bf2(float a, float b) {
    const unsigned ua = __float_as_uint(a) + 0x8000u;
    const unsigned ub = __float_as_uint(b) + 0x8000u;
    return __builtin_amdgcn_perm(ub, ua, 0x07060302u);
}

__device__ __forceinline__ void async_cp16(const unsigned short* g,
                                           const unsigned short* lds_uniform_base) {
    __builtin_amdgcn_global_load_lds(
        (const __attribute__((address_space(1))) unsigned int*)(uintptr_t)g,
        (__attribute__((address_space(3))) unsigned int*)(unsigned int)(uintptr_t)lds_uniform_base,
        16, 0, 0);
}

// ---------------------------------------------------------------------------
// Fused fp32->bf16 cvt, xor-swizzled per 64-el k-block (group g8 -> g8^(n&7)).
// 16 elements/thread. 1D grid: 3*768 activation blocks + 4*144 weight blocks.
// ---------------------------------------------------------------------------
struct CvtArgs { const float* s[7]; };

__global__ __launch_bounds__(256) void cvt_all(CvtArgs a,
                                               unsigned short* __restrict__ Xsw,
                                               unsigned short* __restrict__ Wsw) {
    const int bx = blockIdx.x;
    int y, inner;
    if (bx < 2304) { y = bx / 768;             inner = bx % 768; }
    else           { y = 3 + (bx - 2304) / 144; inner = (bx - 2304) % 144; }
    const int idx = inner * 256 + threadIdx.x;
    const int n  = idx / 48;
    const int g2 = idx % 48;                  // 16-el group in row
    const float* src = a.s[y] + (long)n * D_ + g2 * 16;
    const float zs = (y == 3) ? CSC : 1.0f;
    unsigned short o[16];
#pragma unroll
    for (int i = 0; i < 4; i++) {
        const float4 f = *(const float4*)(src + i * 4);
        o[i*4+0] = f2bf(f.x*zs); o[i*4+1] = f2bf(f.y*zs);
        o[i*4+2] = f2bf(f.z*zs); o[i*4+3] = f2bf(f.w*zs);
    }
    unsigned short* dst = (y >= 3) ? (Wsw + (long)(y - 3) * NW_ + (long)n * D_)
                                   : (Xsw + (long)y * NX_ + (long)n * D_);
    const int key = n & 7;
#pragma unroll
    for (int h = 0; h < 2; h++) {
        const int g8 = g2 * 2 + h;
        const int kdst = (g8 >> 3) * 64 + (((g8 & 7) ^ key) * 8);
        *(uint4*)(dst + kdst) = *(const uint4*)&o[h * 8];
    }
}

// ---------------------------------------------------------------------------
// Fused QKV projection. grid(32, 18): y -> zz = y/6, nb = y%6. Tile 128x128,
// BK=64, 4 waves 2x2. Both operands async-staged from swizzled bf16 global.
// launch_bounds(256,3): all 576 blocks resident (no tail round).
// Outputs: Q/K [bh][s][dk]; V transposed+pi-permuted [bh][dk][s'].
// ---------------------------------------------------------------------------
struct QkvArgs { const float* bias[3]; unsigned short* out[3]; };

__global__ __launch_bounds__(256, 3) void gemm_qkv(QkvArgs args,
                                                   const unsigned short* __restrict__ Xsw,
                                                   const unsigned short* __restrict__ Wsw) {
    __shared__ __align__(16) unsigned short smem[17408];
    unsigned short* As = smem;           // [128][64] swizzled
    unsigned short* Bs = smem + 8192;    // [128][64] swizzled

    const int t    = threadIdx.x;
    const int wave = t >> 6;
    const int lane = t & 63;
    const int l16  = lane & 15;
    const int quad = lane >> 4;
    const int wm   = wave >> 1, wn = wave & 1;
    const int m0   = blockIdx.x * 128;
    const int zz   = blockIdx.y / 6;
    const int nb   = blockIdx.y % 6;
    const int n0   = nb * 128;

    const unsigned short* Ap = Xsw + (long)zz * NX_;
    const unsigned short* Wp = Wsw + (long)zz * NW_;

    f32x4 acc[4][4];
#pragma unroll
    for (int s = 0; s < 4; s++)
#pragma unroll
        for (int j = 0; j < 4; j++) acc[s][j] = (f32x4){0.f, 0.f, 0.f, 0.f};

    const int lrow = lane >> 3;
    const int lcg  = lane & 7;

    for (int k0 = 0; k0 < D_; k0 += 64) {
        __syncthreads();
#pragma unroll
        for (int i = 0; i < 4; i++) {
            const int chunk = wave * 4 + i;
            async_cp16(Ap + (long)(m0 + chunk * 8 + lrow) * D_ + k0 + lcg * 8,
                       As + chunk * 512);
        }
#pragma unroll
        for (int i = 0; i < 4; i++) {
            const int chunk = wave * 4 + i;
            async_cp16(Wp + (long)(n0 + chunk * 8 + lrow) * D_ + k0 + lcg * 8,
                       Bs + chunk * 512);
        }
        __syncthreads();
#pragma unroll
        for (int ks = 0; ks < 2; ks++) {
            const int cg = ks * 4 + quad;
            bf16x8 af[4], bf[4];
#pragma unroll
            for (int s = 0; s < 4; s++) {
                const int r = wm * 64 + s * 16 + l16;
                af[s] = *(const bf16x8*)&As[r * 64 + ((cg ^ (r & 7)) * 8)];
            }
#pragma unroll
            for (int j = 0; j < 4; j++) {
                const int r = wn * 64 + j * 16 + l16;
                bf[j] = *(const bf16x8*)&Bs[r * 64 + ((cg ^ (r & 7)) * 8)];
            }
#pragma unroll
            for (int s = 0; s < 4; s++)
#pragma unroll
                for (int j = 0; j < 4; j++)
                    acc[s][j] = __builtin_amdgcn_mfma_f32_16x16x32_bf16(af[s], bf[j], acc[s][j], 0, 0, 0);
        }
    }
    __syncthreads();

    const int b     = m0 >> 11;
    const int sbase = m0 & (S_ - 1);
    const float zs  = (zz == 0) ? CSC : 1.0f;
    float bv[4];
#pragma unroll
    for (int j = 0; j < 4; j++) bv[j] = args.bias[zz][n0 + wn * 64 + j * 16 + l16] * zs;

    if (zz < 2) {
        unsigned short* Ls = smem;       // [128][136]
#pragma unroll
        for (int s = 0; s < 4; s++)
#pragma unroll
            for (int j = 0; j < 4; j++)
#pragma unroll
                for (int r = 0; r < 4; r++)
                    Ls[(wm * 64 + s * 16 + quad * 4 + r) * 136 + wn * 64 + j * 16 + l16] =
                        f2bf(acc[s][j][r] + bv[j]);
        __syncthreads();
        const int row  = t >> 1;
        const int half = t & 1;
        unsigned short* Op = args.out[zz];
#pragma unroll
        for (int i = 0; i < 8; i++) {
            const int col  = half * 64 + i * 8;
            const int head = nb * 2 + half;
            const uint4 v = *(const uint4*)&Ls[row * 136 + col];
            *(uint4*)(Op + ((long)(b * H_ + head) * S_ + sbase + row) * DK_ + (col & 63)) = v;
        }
    } else {
        unsigned short* Ls = smem;       // [2][64][136]
#pragma unroll
        for (int s = 0; s < 4; s++)
#pragma unroll
            for (int j = 0; j < 4; j++)
#pragma unroll
                for (int r = 0; r < 4; r++) {
                    const int dk  = j * 16 + l16;
                    const int pos = wm * 64 + (quad * 4 + r) * 4 + s;   // pi-permute
                    Ls[wn * 8704 + dk * 136 + pos] = f2bf(acc[s][j][r] + bv[j]);
                }
        __syncthreads();
        const int rowIdx = t >> 1;
        const int hh = rowIdx >> 6, dk = rowIdx & 63;
        const int half = t & 1;
        unsigned short* Op = args.out[2];
#pragma unroll
        for (int i = 0; i < 8; i++) {
            const int col = half * 64 + i * 8;
            const uint4 v = *(const uint4*)&Ls[hh * 8704 + dk * 136 + col];
            const int head = nb * 2 + hh;
            *(uint4*)(Op + ((long)(b * H_ + head) * DK_ + dk) * S_ + sbase + col) = v;
        }
    }
}

// ---------------------------------------------------------------------------
// Flash attention: R7 structure (proven 60.6 us). 64-row q-tiles, 4 waves.
// XCD-LOCAL GRID: 1D grid of 768, bh = bid % 24, qtile = bid / 24. Since
// dispatch round-robins blocks over 8 XCDs and 24 % 8 == 0, all 32 q-tile
// blocks of one (b,h) land on ONE XCD -> that head's 512 KB K/V stays in the
// XCD-private 4 MB L2 (3 heads/XCD = 1.5 MB + Q streams). Was: same-head
// blocks spread over all XCDs -> 393 MB of L3 traffic at ~6.4 TB/s ceiling.
// No-max softmax (scale baked into Q), pi-permuted packed P-stores, piV,
// double-buffered K/V LDS + register prefetch with rolling pointers.
// ---------------------------------------------------------------------------
__global__ __launch_bounds__(256, 3) void attn_kernel(
    const unsigned short* __restrict__ Q, const unsigned short* __restrict__ K,
    const unsigned short* __restrict__ Vt, unsigned short* __restrict__ Ao)
{
    const int t    = threadIdx.x;
    const int wave = t >> 6;
    const int lane = t & 63;
    const int l16  = lane & 15;
    const int quad = lane >> 4;
    const int bid  = blockIdx.x;        // 768 blocks, 1D
    const int bh    = bid % 24;         // XCD = bid % 8 -> bh % 8: head-local L2
    const int qtile = bid / 24;         // 32 tiles of 64 rows

    const unsigned short* Qp = Q  + (long)bh * S_ * DK_;
    const unsigned short* Kp = K  + (long)bh * S_ * DK_;
    const unsigned short* Vp = Vt + (long)bh * DK_ * S_;

    __shared__ __align__(16) unsigned short smem[23040];   // 45 KB
    // Ks0@0  Ks1@4608  Vs0@9216  Vs1@13824  Ps@18432  (each [64][72])
    unsigned short* Ps = smem + 18432;

    bf16x8 qfrag[2];
    {
        const long qoff = (long)(qtile * 64 + wave * 16 + l16) * DK_ + quad * 8;
        qfrag[0] = *(const bf16x8*)(Qp + qoff);
        qfrag[1] = *(const bf16x8*)(Qp + qoff + 32);
    }

    const int srow = t >> 2;            // 0..63
    const int scg  = (t & 3) * 16;
    uint4 kreg[2], vreg[2];
    // rolling source pointers
    const unsigned short* gk = Kp + (long)srow * DK_ + scg;
    const unsigned short* gv = Vp + (long)srow * S_ + scg;
    // tile 0 -> buffer 0
    kreg[0] = *(const uint4*)gk;  kreg[1] = *(const uint4*)(gk + 8);
    vreg[0] = *(const uint4*)gv;  vreg[1] = *(const uint4*)(gv + 8);
    gk += 64 * DK_;  gv += 64;
    *(uint4*)&smem[srow * 72 + scg]            = kreg[0];
    *(uint4*)&smem[srow * 72 + scg + 8]        = kreg[1];
    *(uint4*)&smem[9216 + srow * 72 + scg]     = vreg[0];
    *(uint4*)&smem[9216 + srow * 72 + scg + 8] = vreg[1];

    f32x4 oacc[4];
#pragma unroll
    for (int j = 0; j < 4; j++) oacc[j] = (f32x4){0.f, 0.f, 0.f, 0.f};
    float lsum[4] = {0.f, 0.f, 0.f, 0.f};

    for (int it = 0; it < 32; ++it) {
        const int co = (it & 1) * 4608;          // current buffer offset
        const int no = ((it & 1) ^ 1) * 4608;    // next buffer offset
        __syncthreads();                 // prev-iter commits visible
        const unsigned short* Ks = smem + co;
        const unsigned short* Vs = smem + 9216 + co;

        if (it < 31) {                   // prefetch next tile into registers
            kreg[0] = *(const uint4*)gk;  kreg[1] = *(const uint4*)(gk + 8);
            vreg[0] = *(const uint4*)gv;  vreg[1] = *(const uint4*)(gv + 8);
            gk += 64 * DK_;  gv += 64;
        }

        // S = Q K^T
        f32x4 sacc[4];
#pragma unroll
        for (int j = 0; j < 4; j++) sacc[j] = (f32x4){0.f, 0.f, 0.f, 0.f};
#pragma unroll
        for (int ks = 0; ks < 2; ks++)
#pragma unroll
            for (int j = 0; j < 4; j++) {
                const bf16x8 bf = *(const bf16x8*)&Ks[(j * 16 + l16) * 72 + ks * 32 + quad * 8];
                sacc[j] = __builtin_amdgcn_mfma_f32_16x16x32_bf16(qfrag[ks], bf, sacc[j], 0, 0, 0);
            }

        // p = exp2(s); packed b64 P-stores, pi-permuted columns
#pragma unroll
        for (int r = 0; r < 4; r++) {
            const float p0 = exp2f(sacc[0][r]);
            const float p1 = exp2f(sacc[1][r]);
            const float p2 = exp2f(sacc[2][r]);
            const float p3 = exp2f(sacc[3][r]);
            lsum[r] += (p0 + p1) + (p2 + p3);
            uint2 pk = {pack_bf2(p0, p1), pack_bf2(p2, p3)};
            *(uint2*)&Ps[(wave * 16 + quad * 4 + r) * 72 + l16 * 4] = pk;
        }

        // O += P V (wave-local P rows: lgkmcnt ordering only, no barrier)
#pragma unroll
        for (int ks = 0; ks < 2; ks++) {
            const bf16x8 pf = *(const bf16x8*)&Ps[(wave * 16 + l16) * 72 + ks * 32 + quad * 8];
#pragma unroll
            for (int j = 0; j < 4; j++) {
                const bf16x8 vf = *(const bf16x8*)&Vs[(j * 16 + l16) * 72 + ks * 32 + quad * 8];
                oacc[j] = __builtin_amdgcn_mfma_f32_16x16x32_bf16(pf, vf, oacc[j], 0, 0, 0);
            }
        }

        if (it < 31) {                   // commit prefetch to other buffer
            *(uint4*)&smem[no + srow * 72 + scg]            = kreg[0];
            *(uint4*)&smem[no + srow * 72 + scg + 8]        = kreg[1];
            *(uint4*)&smem[9216 + no + srow * 72 + scg]     = vreg[0];
            *(uint4*)&smem[9216 + no + srow * 72 + scg + 8] = vreg[1];
        }
    }

#pragma unroll
    for (int r = 0; r < 4; r++) {
#pragma unroll
        for (int off = 1; off < 16; off <<= 1)
            lsum[r] += __shfl_xor(lsum[r], off, 64);
        lsum[r] = 1.f / lsum[r];
    }

    // epilogue: bf16 via LDS (wave-local rows of Ps), b128 swizzled stores
    __syncthreads();
#pragma unroll
    for (int j = 0; j < 4; j++)
#pragma unroll
        for (int r = 0; r < 4; r++)
            Ps[(wave * 16 + quad * 4 + r) * 72 + j * 16 + l16] =
                f2bf(oacc[j][r] * lsum[r]);

    const int b = bh / H_, h = bh % H_;
    const int row = t >> 2;             // wave-local rows: no barrier needed
    const int c0  = (t & 3) * 16;
    const int qrow = qtile * 64 + row;
    const int key  = qrow & 7;
    const uint4 v0 = *(const uint4*)&Ps[row * 72 + c0];
    const uint4 v1 = *(const uint4*)&Ps[row * 72 + c0 + 8];
    const int g8 = c0 >> 3;
    unsigned short* dst = Ao + (long)(b * S_ + qrow) * D_ + h * DK_;
    *(uint4*)(dst + ((g8 ^ key) * 8))       = v0;
    *(uint4*)(dst + (((g8 + 1) ^ key) * 8)) = v1;
}

// ---------------------------------------------------------------------------
// Output projection: Ao_sw bf16 @ Wo_sw -> fp32 d_out + bias. Tile 64x64,
// grid (64,12)=768 = 3/CU; launch_bounds(256,4) so all blocks resident.
// 4 waves 2x2 (wave 32x32), both operands async. Single-pass LDS epilogue.
// ---------------------------------------------------------------------------
__global__ __launch_bounds__(256, 4) void gemm_out(
    const unsigned short* __restrict__ A, const unsigned short* __restrict__ Wsw,
    const float* __restrict__ bias, float* __restrict__ Out)
{
    __shared__ __align__(16) unsigned short smem[8704];
    unsigned short* As = smem;           // [64][64] swizzled
    unsigned short* Bs = smem + 4096;    // [64][64] swizzled

    const int t    = threadIdx.x;
    const int wave = t >> 6;
    const int lane = t & 63;
    const int l16  = lane & 15;
    const int quad = lane >> 4;
    const int wm   = wave >> 1, wn = wave & 1;
    const int m0   = blockIdx.x * 64;
    const int n0   = blockIdx.y * 64;

    f32x4 acc[2][2];
#pragma unroll
    for (int s = 0; s < 2; s++)
#pragma unroll
        for (int j = 0; j < 2; j++) acc[s][j] = (f32x4){0.f, 0.f, 0.f, 0.f};

    const int lrow = lane >> 3;
    const int lcg  = lane & 7;

    for (int k0 = 0; k0 < D_; k0 += 64) {
        __syncthreads();
#pragma unroll
        for (int i = 0; i < 2; i++) {
            const int chunk = wave * 2 + i;
            async_cp16(A + (long)(m0 + chunk * 8 + lrow) * D_ + k0 + lcg * 8,
                       As + chunk * 512);
        }
#pragma unroll
        for (int i = 0; i < 2; i++) {
            const int chunk = wave * 2 + i;
            async_cp16(Wsw + (long)(n0 + chunk * 8 + lrow) * D_ + k0 + lcg * 8,
                       Bs + chunk * 512);
        }
        __syncthreads();
#pragma unroll
        for (int ks = 0; ks < 2; ks++) {
            const int cg = ks * 4 + quad;
            bf16x8 af[2], bf[2];
#pragma unroll
            for (int s = 0; s < 2; s++) {
                const int r = wm * 32 + s * 16 + l16;
                af[s] = *(const bf16x8*)&As[r * 64 + ((cg ^ (r & 7)) * 8)];
            }
#pragma unroll
            for (int j = 0; j < 2; j++) {
                const int r = wn * 32 + j * 16 + l16;
                bf[j] = *(const bf16x8*)&Bs[r * 64 + ((cg ^ (r & 7)) * 8)];
            }
#pragma unroll
            for (int s = 0; s < 2; s++)
#pragma unroll
                for (int j = 0; j < 2; j++)
                    acc[s][j] = __builtin_amdgcn_mfma_f32_16x16x32_bf16(af[s], bf[j], acc[s][j], 0, 0, 0);
        }
    }

    float bv[2];
#pragma unroll
    for (int j = 0; j < 2; j++) bv[j] = bias[n0 + wn * 32 + j * 16 + l16];

    __syncthreads();                     // done with As/Bs before reuse
    float* fl = (float*)smem;            // [64][67]
#pragma unroll
    for (int s = 0; s < 2; s++)
#pragma unroll
        for (int j = 0; j < 2; j++)
#pragma unroll
            for (int r = 0; r < 4; r++)
                fl[(wm * 32 + s * 16 + quad * 4 + r) * 67 + wn * 32 + j * 16 + l16] =
                    acc[s][j][r] + bv[j];
    __syncthreads();
    const int row = t >> 2, c0 = (t & 3) * 16;
#pragma unroll
    for (int i = 0; i < 4; i++) {
        const float4 v = *(const float4*)&fl[row * 67 + c0 + i * 4];
        *(float4*)(Out + (long)(m0 + row) * D_ + n0 + c0 + i * 4) = v;
    }
}

extern "C" void kernel_launch(void* const* d_in, const int* in_sizes, int n_in,
                              void* d_out, int out_size, void* d_ws, size_t ws_size,
                              hipStream_t stream) {
    const float* k_in = (const float*)d_in[0];
    const float* q_in = (const float*)d_in[1];
    const float* v_in = (const float*)d_in[2];
    // d_in[3] = mask: no-op per reference
    const float* wq = (const float*)d_in[4];
    const float* bq = (const float*)d_in[5];
    const float* wk = (const float*)d_in[6];
    const float* bk = (const float*)d_in[7];
    const float* wv = (const float*)d_in[8];
    const float* bv = (const float*)d_in[9];
    const float* wo = (const float*)d_in[10];
    const float* bo = (const float*)d_in[11];

    unsigned short* ws = (unsigned short*)d_ws;
    unsigned short* Wsw = ws;                          // 4*NW bf16 swizzled
    unsigned short* Qb  = Wsw + 4ll * NW_;             // NX bf16
    unsigned short* Kb  = Qb + (long)NX_;
    unsigned short* Vt  = Kb + (long)NX_;
    unsigned short* Xsw = Vt + (long)NX_;              // 3*NX (dead after qkv)
    unsigned short* Ao  = Xsw;                         // aliases Xsw

    CvtArgs ca;
    ca.s[0] = q_in; ca.s[1] = k_in; ca.s[2] = v_in;
    ca.s[3] = wq;   ca.s[4] = wk;   ca.s[5] = wv;  ca.s[6] = wo;
    cvt_all<<<dim3(2880), 256, 0, stream>>>(ca, Xsw, Wsw);

    QkvArgs qa;
    qa.bias[0] = bq; qa.bias[1] = bk; qa.bias[2] = bv;
    qa.out[0] = Qb;  qa.out[1] = Kb;  qa.out[2] = Vt;
    gemm_qkv<<<dim3(32, 18), 256, 0, stream>>>(qa, Xsw, Wsw);

    attn_kernel<<<dim3(768), 256, 0, stream>>>(Qb, Kb, Vt, Ao);

    gemm_out<<<dim3(64, 12), 256, 0, stream>>>(Ao, Wsw + 3ll * NW_, bo, (float*)d_out);
}